// Round 18
// baseline (311.114 us; speedup 1.0000x reference)
//
#include <hip/hip_runtime.h>
#include <hip/hip_fp16.h>

// GCN 2-layer via CSR gather. G tables + x2 in fp16. Rank-capture CSR build.
// NEW: feature-chunked gather — 32-feature chunks (3.2 MB table slice < 4 MB
// per-XCD L2), chunk-major grid so the random gather hits L2, not HBM.
// out = dinv ⊙ (A · (dinv ⊙ (relu(dinv ⊙ (A · (dinv ⊙ (x@W1))) + b1) @ W2))) + b2

constexpr int DIN = 128;

// ---- degree histogram + per-edge rank capture (2 edges/thread) -------------
__global__ void count_deg_k(const int* __restrict__ dst, int* __restrict__ cnt,
                            int* __restrict__ rank, int e2, int e) {
    int i = blockIdx.x * 256 + threadIdx.x;
    if (i >= e2) return;
    int2 d = reinterpret_cast<const int2*>(dst)[i];
    int r0 = atomicAdd(&cnt[d.x], 1);
    int r1 = (2 * i + 1 < e) ? atomicAdd(&cnt[d.y], 1) : 0;
    reinterpret_cast<int2*>(rank)[i] = make_int2(r0, r1);
}

// ---- hierarchical exclusive scan + fused dinv ------------------------------
__global__ __launch_bounds__(256) void scan1_k(const int* __restrict__ cnt,
                                               int* __restrict__ rowptr,
                                               int* __restrict__ bsum,
                                               float* __restrict__ dinv,
                                               int n_out, int n_cnt) {
    __shared__ int wsum[4];
    const int tid  = threadIdx.x;
    const int lane = tid & 63;
    const int wv   = tid >> 6;
    const int base = blockIdx.x * 1024 + tid * 4;

    int v0 = (base + 0 < n_cnt) ? cnt[base + 0] : 0;
    int v1 = (base + 1 < n_cnt) ? cnt[base + 1] : 0;
    int v2 = (base + 2 < n_cnt) ? cnt[base + 2] : 0;
    int v3 = (base + 3 < n_cnt) ? cnt[base + 3] : 0;
    int tsum = v0 + v1 + v2 + v3;

    if (base + 0 < n_cnt) dinv[base + 0] = rsqrtf((float)v0 + 1.0f);
    if (base + 1 < n_cnt) dinv[base + 1] = rsqrtf((float)v1 + 1.0f);
    if (base + 2 < n_cnt) dinv[base + 2] = rsqrtf((float)v2 + 1.0f);
    if (base + 3 < n_cnt) dinv[base + 3] = rsqrtf((float)v3 + 1.0f);

    int incl = tsum;
    for (int d = 1; d < 64; d <<= 1) {
        int t = __shfl_up(incl, d, 64);
        if (lane >= d) incl += t;
    }
    if (lane == 63) wsum[wv] = incl;
    __syncthreads();
    int woff = 0;
    for (int w = 0; w < wv; ++w) woff += wsum[w];
    int excl = woff + incl - tsum;

    int e0 = excl;
    int e1 = e0 + v0;
    int e2 = e1 + v1;
    int e3 = e2 + v2;
    if (base + 0 < n_out) rowptr[base + 0] = e0;
    if (base + 1 < n_out) rowptr[base + 1] = e1;
    if (base + 2 < n_out) rowptr[base + 2] = e2;
    if (base + 3 < n_out) rowptr[base + 3] = e3;

    if (tid == 255) bsum[blockIdx.x] = woff + incl;
}

__global__ __launch_bounds__(1024) void scan2_k(int* __restrict__ bsum, int nb) {
    __shared__ int sh[1024];
    const int t = threadIdx.x;
    int v = (t < nb) ? bsum[t] : 0;
    sh[t] = v;
    __syncthreads();
    for (int d = 1; d < 1024; d <<= 1) {
        int x = (t >= d) ? sh[t - d] : 0;
        __syncthreads();
        sh[t] += x;
        __syncthreads();
    }
    if (t < nb) bsum[t] = sh[t] - v;
}

__global__ void scan3_k(int* __restrict__ rowptr, const int* __restrict__ bsum, int n_out) {
    int i = blockIdx.x * 256 + threadIdx.x;
    if (i < n_out) rowptr[i] += bsum[i >> 10];
}

// fill: no atomic — pos = rowptr[dst] + rank  (2 edges/thread)
__global__ void fill_k(const int* __restrict__ src, const int* __restrict__ dst,
                       const int* __restrict__ rowptr, const int* __restrict__ rank,
                       int* __restrict__ col, int e2, int e) {
    int i = blockIdx.x * 256 + threadIdx.x;
    if (i >= e2) return;
    int2 d = reinterpret_cast<const int2*>(dst)[i];
    int2 r = reinterpret_cast<const int2*>(rank)[i];
    int2 s = reinterpret_cast<const int2*>(src)[i];
    col[rowptr[d.x] + r.x] = s.x;
    if (2 * i + 1 < e) col[rowptr[d.y] + r.y] = s.y;
}

// ---- fused GEMM + row scale -> fp16:  G = fp16(dinv[:,None] * (X @ W)) -----
template <typename TIN, int DOUT>
__global__ __launch_bounds__(256, 4) void gemm_scale_k(
    const TIN* __restrict__ X, const float* __restrict__ W,
    const float* __restrict__ dinv, __half* __restrict__ G, int N)
{
    constexpr int TM = 64;
    constexpr int C4 = DOUT / 4;
    constexpr int GROUPS = 256 / C4;
    constexpr int RPT = TM / GROUPS;

    __shared__ TIN sX[TM * DIN];

    const int tid  = threadIdx.x;
    const int base = blockIdx.x * TM;
    const float4* Wv = reinterpret_cast<const float4*>(W);

    constexpr int EPL = 16 / sizeof(TIN);
    for (int idx = tid; idx < TM * DIN / EPL; idx += 256) {
        int row  = idx / (DIN / EPL);
        int grow = base + row;
        uint4 v = make_uint4(0u, 0u, 0u, 0u);
        if (grow < N)
            v = reinterpret_cast<const uint4*>(X)[(size_t)grow * (DIN / EPL) + (idx % (DIN / EPL))];
        reinterpret_cast<uint4*>(sX)[idx] = v;
    }
    __syncthreads();

    const int cq = tid % C4;
    const int rg = tid / C4;

    float4 acc[RPT];
#pragma unroll
    for (int r = 0; r < RPT; ++r) acc[r] = make_float4(0.f, 0.f, 0.f, 0.f);

#pragma unroll 4
    for (int k = 0; k < DIN; ++k) {
        float4 w = Wv[k * C4 + cq];
#pragma unroll
        for (int r = 0; r < RPT; ++r) {
            float xv;
            if constexpr (sizeof(TIN) == 4) xv = ((const float*)sX)[(rg + r * GROUPS) * DIN + k];
            else                            xv = __half2float(((const __half*)sX)[(rg + r * GROUPS) * DIN + k]);
            acc[r].x = fmaf(xv, w.x, acc[r].x);
            acc[r].y = fmaf(xv, w.y, acc[r].y);
            acc[r].z = fmaf(xv, w.z, acc[r].z);
            acc[r].w = fmaf(xv, w.w, acc[r].w);
        }
    }

#pragma unroll
    for (int r = 0; r < RPT; ++r) {
        int row = base + rg + r * GROUPS;
        if (row < N) {
            float dv = dinv[row];
            __half2 p0 = __floats2half2_rn(acc[r].x * dv, acc[r].y * dv);
            __half2 p1 = __floats2half2_rn(acc[r].z * dv, acc[r].w * dv);
            uint2 packed = make_uint2(*reinterpret_cast<unsigned*>(&p0),
                                      *reinterpret_cast<unsigned*>(&p1));
            *reinterpret_cast<uint2*>(G + (size_t)row * DOUT + cq * 4) = packed;
        }
    }
}

// ---- feature-chunked gather (fp16 table, f32 accumulate) -------------------
// CHUNK=32 features per pass; chunk-major grid => the live 3.2 MB table slice
// is L2-resident per XCD. Per wave: one node × one chunk; QL=4 lanes/row-chunk,
// NS=16 edge slots. shfl_xor tree combines slots.
template <int D, int NCHUNK, bool RELU, typename TOUT>
__global__ __launch_bounds__(256) void gather_chunk_k(
    const __half* __restrict__ G, const int* __restrict__ rowptr,
    const int* __restrict__ col, const float* __restrict__ dinv,
    const float* __restrict__ bias, TOUT* __restrict__ out, int N)
{
    constexpr int CHUNK = D / NCHUNK;       // 32
    constexpr int QL = CHUNK / 8;           // lanes per row-chunk: 4
    constexpr int NS = 64 / QL;             // edge slots: 16
    constexpr int RS = D / 8;               // uint4 per full row

    const int gwave = (blockIdx.x * 256 + threadIdx.x) >> 6;
    if (gwave >= N * NCHUNK) return;
    const int chunk = gwave / N;            // chunk-major: slowest-varying
    const int node  = gwave - chunk * N;
    const int lane  = threadIdx.x & 63;
    const int q     = lane % QL;
    const int slot  = lane / QL;
    const int cb    = chunk * QL;           // uint4 offset of chunk within row

    const uint4* G4 = reinterpret_cast<const uint4*>(G);

    float acc[8];
#pragma unroll
    for (int k = 0; k < 8; ++k) acc[k] = 0.f;

    auto accum = [&](uint4 raw) {
        const __half2* hp = reinterpret_cast<const __half2*>(&raw);
#pragma unroll
        for (int p = 0; p < 4; ++p) {
            float2 f = __half22float2(hp[p]);
            acc[2 * p]     += f.x;
            acc[2 * p + 1] += f.y;
        }
    };

    if (slot == 0) accum(G4[(size_t)node * RS + cb + q]);   // self-loop
    const int beg = rowptr[node], end = rowptr[node + 1];

    int j = beg;
    for (; j + NS <= end; j += NS) {
        int s = col[j + slot];
        accum(G4[(size_t)s * RS + cb + q]);
    }
    {
        int rem = end - j;
        if (slot < rem) {
            int s = col[j + slot];
            accum(G4[(size_t)s * RS + cb + q]);
        }
    }

#pragma unroll
    for (int d = QL; d < 64; d <<= 1) {
#pragma unroll
        for (int k = 0; k < 8; ++k) acc[k] += __shfl_xor(acc[k], d, 64);
    }

    if (lane < QL) {
        float dv = dinv[node];
        const float4* bb = reinterpret_cast<const float4*>(bias + chunk * CHUNK + q * 8);
        float4 b0 = bb[0], b1 = bb[1];
        float o[8];
        o[0] = dv * acc[0] + b0.x;  o[1] = dv * acc[1] + b0.y;
        o[2] = dv * acc[2] + b0.z;  o[3] = dv * acc[3] + b0.w;
        o[4] = dv * acc[4] + b1.x;  o[5] = dv * acc[5] + b1.y;
        o[6] = dv * acc[6] + b1.z;  o[7] = dv * acc[7] + b1.w;
        if constexpr (RELU) {
#pragma unroll
            for (int k = 0; k < 8; ++k) o[k] = fmaxf(o[k], 0.f);
        }
        if constexpr (sizeof(TOUT) == 2) {
            __half2 h0 = __floats2half2_rn(o[0], o[1]);
            __half2 h1 = __floats2half2_rn(o[2], o[3]);
            __half2 h2 = __floats2half2_rn(o[4], o[5]);
            __half2 h3 = __floats2half2_rn(o[6], o[7]);
            uint4 packed = make_uint4(*reinterpret_cast<unsigned*>(&h0),
                                      *reinterpret_cast<unsigned*>(&h1),
                                      *reinterpret_cast<unsigned*>(&h2),
                                      *reinterpret_cast<unsigned*>(&h3));
            reinterpret_cast<uint4*>((__half*)out + (size_t)node * D + chunk * CHUNK)[q] = packed;
        } else {
            float4* op = reinterpret_cast<float4*>((float*)out + (size_t)node * D + chunk * CHUNK + q * 8);
            op[0] = make_float4(o[0], o[1], o[2], o[3]);
            op[1] = make_float4(o[4], o[5], o[6], o[7]);
        }
    }
}

static inline size_t align256(size_t x) { return (x + 255) & ~size_t(255); }

extern "C" void kernel_launch(void* const* d_in, const int* in_sizes, int n_in,
                              void* d_out, int out_size, void* d_ws, size_t ws_size,
                              hipStream_t stream) {
    const float* e_prev = (const float*)d_in[0];
    const int*   eidx   = (const int*)d_in[1];
    const float* W1     = (const float*)d_in[2];
    const float* b1     = (const float*)d_in[3];
    const float* W2     = (const float*)d_in[4];
    const float* b2     = (const float*)d_in[5];

    const int dh   = in_sizes[3];            // 128
    const int din  = in_sizes[2] / dh;       // 128
    const int N    = in_sizes[0] / din;      // 50000
    const int E    = in_sizes[1] / 2;        // 800000
    (void)dh;

    const int* src = eidx;
    const int* dst = eidx + E;

    // workspace layout
    char* ws = (char*)d_ws;
    size_t off = 0;
    int*    cnt    = (int*)(ws + off);    off = align256(off + (size_t)N * 4);
    float*  dinv   = (float*)(ws + off);  off = align256(off + (size_t)N * 4);
    int*    rowptr = (int*)(ws + off);    off = align256(off + (size_t)(N + 1) * 4);
    int*    bsum   = (int*)(ws + off);    off = align256(off + (size_t)1024 * 4);
    int*    col    = (int*)(ws + off);    off = align256(off + (size_t)E * 4);
    int*    rank   = (int*)(ws + off);    off = align256(off + (size_t)E * 4);
    __half* gh     = (__half*)(ws + off); off = align256(off + (size_t)N * DIN * 2);  // fp16 G
    __half* x2h    = (__half*)(ws + off); off = align256(off + (size_t)N * DIN * 2);  // fp16 x2
    (void)ws_size;

    float* outp = (float*)d_out;

    const int T = 256;
    const int E2 = (E + 1) / 2;
    const int gE2 = (E2 + T - 1) / T;
    const int n_out = N + 1;
    const int nb = (n_out + 1023) / 1024;

    // ---- CSR build ----
    hipMemsetAsync(cnt, 0, (size_t)N * 4, stream);
    count_deg_k<<<gE2, T, 0, stream>>>(dst, cnt, rank, E2, E);
    scan1_k<<<nb, T, 0, stream>>>(cnt, rowptr, bsum, dinv, n_out, N);
    scan2_k<<<1, 1024, 0, stream>>>(bsum, nb);
    scan3_k<<<(n_out + T - 1) / T, T, 0, stream>>>(rowptr, bsum, n_out);
    fill_k<<<gE2, T, 0, stream>>>(src, dst, rowptr, rank, col, E2, E);

    // ---- layer 1 (gather: 4 chunks of 32 feats, chunk-major) ----
    gemm_scale_k<float, 128><<<(N + 63) / 64, T, 0, stream>>>(e_prev, W1, dinv, gh, N);
    {
        int waves = N * 4;
        gather_chunk_k<128, 4, true, __half><<<(waves + 3) / 4, T, 0, stream>>>(
            gh, rowptr, col, dinv, b1, x2h, N);
    }

    // ---- layer 2 (gather: 2 chunks of 32 feats) ----
    gemm_scale_k<__half, 64><<<(N + 63) / 64, T, 0, stream>>>(x2h, W2, dinv, gh, N);
    {
        int waves = N * 2;
        gather_chunk_k<64, 2, false, float><<<(waves + 3) / 4, T, 0, stream>>>(
            gh, rowptr, col, dinv, b2, outp, N);
    }
}